// Round 18
// baseline (1112.929 us; speedup 1.0000x reference)
//
#include <hip/hip_runtime.h>
#include <hip/hip_bf16.h>
#include <math.h>

typedef __hip_bfloat16 bf16;
typedef __attribute__((ext_vector_type(4))) float f32x4;
typedef __attribute__((ext_vector_type(8))) short short8;

constexpr int Bc = 2, Tc = 1024, Dc = 1024, Hc = 16, Lc = 4, MLPc = 4096, Vc = 32000, HDc = 64;

__device__ __forceinline__ unsigned short f2bu(float f) {
    __hip_bfloat16 h = __float2bfloat16(f);
    unsigned short u;
    __builtin_memcpy(&u, &h, 2);
    return u;
}
__device__ __forceinline__ float bu2f(unsigned short u) {
    __hip_bfloat16 h;
    __builtin_memcpy(&h, &u, 2);
    return __bfloat162float(h);
}

__device__ __forceinline__ void gl2lds16(const bf16* g, bf16* l) {
    __builtin_amdgcn_global_load_lds(
        (const __attribute__((address_space(1))) void*)g,
        (__attribute__((address_space(3))) void*)l, 16, 0, 0);
}

enum { EPI_BIAS_BF16 = 0, EPI_GELU = 1, EPI_RESADD = 2, EPI_F32 = 3, EPI_QKV = 4 };

template <int EPI>
__device__ __forceinline__ void epi_store(float v, int row, int col, void* Cv,
                                          int ldc, const float* bias) {
    if constexpr (EPI == EPI_BIAS_BF16) {
        v += bias[col];
        ((bf16*)Cv)[(size_t)row * ldc + col] = __float2bfloat16(v);
    } else if constexpr (EPI == EPI_GELU) {
        v += bias[col];
        v = 0.5f * v * (1.0f + erff(v * 0.70710678118f));
        ((bf16*)Cv)[(size_t)row * ldc + col] = __float2bfloat16(v);
    } else if constexpr (EPI == EPI_RESADD) {
        bf16* C = (bf16*)Cv;
        size_t idx = (size_t)row * ldc + col;
        float xo = __bfloat162float(C[idx]);
        C[idx] = __float2bfloat16(xo + v + bias[col]);
    } else if constexpr (EPI == EPI_F32) {
        ((float*)Cv)[(size_t)row * ldc + col] = v;
    } else if constexpr (EPI == EPI_QKV) {
        v += bias[col];
        bf16 bv = __float2bfloat16(v);
        int b = row >> 10, t = row & 1023;
        int seg = col >> 10;
        int cc = col & 1023;
        int h = cc >> 6, hd = cc & 63;
        bf16* base = (bf16*)Cv;
        base[(size_t)seg * 2097152 + ((size_t)(b * Hc + h) * Tc + t) * HDc + hd] = bv;
    }
}

// ---------- 256x256 GEMM, m201-faithful pipeline (round-15 best: ~195us lm_head) ----------
template <int EPI>
__global__ __launch_bounds__(512) void gemm_8p(
    const bf16* __restrict__ A, int lda,
    const bf16* __restrict__ Bm, int ldb,
    void* __restrict__ Cv, int ldc,
    const float* __restrict__ bias, int K)
{
    constexpr int BM = 256, BN = 256, BK = 64;
    __shared__ alignas(16) bf16 As[2][BM][BK];
    __shared__ alignas(16) bf16 Bs[2][BN][BK];

    const int tid = threadIdx.x;
    const int lane = tid & 63;
    const int w = tid >> 6;
    const int wm = w >> 2;
    const int wn = w & 3;

    int nwg = gridDim.x * gridDim.y;
    int orig = blockIdx.y * gridDim.x + blockIdx.x;
    int q = nwg >> 3, rr = nwg & 7, xcd = orig & 7, lid = orig >> 3;
    int wg = (xcd < rr ? xcd * (q + 1) : rr * (q + 1) + (xcd - rr) * q) + lid;
    int im = wg % gridDim.x;
    int in = wg / gridDim.x;

    const bf16* Ab = A + (size_t)im * BM * lda;
    const bf16* Bb = Bm + (size_t)in * BN * ldb;

    const int sr = lane >> 3;
    const int scs = ((lane & 7) ^ sr) * 8;
    const int lr = lane & 15, lq = lane >> 4;

    f32x4 acc[2][2][4][2];
#pragma unroll
    for (int a = 0; a < 2; a++)
#pragma unroll
        for (int b = 0; b < 2; b++)
#pragma unroll
            for (int c = 0; c < 4; c++)
#pragma unroll
                for (int d = 0; d < 2; d++) acc[a][b][c][d] = (f32x4){0.f, 0.f, 0.f, 0.f};

    const int NT = K / BK;

    auto stage_half = [&](int buf, int sg, int k0) {
        const bool isB = (sg == 1 || sg == 2);
        const bf16* gp = isB ? Bb : Ab;
        const int ld = isB ? ldb : lda;
        bf16* ls = isB ? &Bs[buf][0][0] : &As[buf][0][0];
        const int half = (sg == 2 || sg == 3) ? 1 : 0;
#pragma unroll
        for (int i = 0; i < 2; i++) {
            int r0 = half * 128 + i * 64 + w * 8;
            gl2lds16(gp + (size_t)(r0 + sr) * ld + k0 + scs, ls + r0 * BK);
        }
    };

#pragma unroll
    for (int sg = 0; sg < 4; sg++) stage_half(0, sg, 0);
#pragma unroll
    for (int sg = 0; sg < 4; sg++) stage_half(1, sg, BK);
    asm volatile("s_waitcnt vmcnt(8)" ::: "memory");
    __builtin_amdgcn_s_barrier();
    asm volatile("" ::: "memory");

    short8 af[4][2], bfv0[2][2], bfv1[2][2];

    auto load_af8 = [&](const char* Abase, int mh) {
#pragma unroll
        for (int fi = 0; fi < 4; fi++) {
            int r = mh * 128 + wm * 64 + fi * 16 + lr;
#pragma unroll
            for (int kk = 0; kk < 2; kk++) {
                int cb = (kk * 64 + lq * 16) ^ ((r & 7) << 4);
                af[fi][kk] = *reinterpret_cast<const short8*>(Abase + (size_t)r * 128 + cb);
            }
        }
    };
    auto load_bf4 = [&](const char* Bbase, int nh, short8 (&bfv)[2][2]) {
#pragma unroll
        for (int fj = 0; fj < 2; fj++) {
            int r = nh * 128 + wn * 32 + fj * 16 + lr;
#pragma unroll
            for (int kk = 0; kk < 2; kk++) {
                int cb = (kk * 64 + lq * 16) ^ ((r & 7) << 4);
                bfv[fj][kk] = *reinterpret_cast<const short8*>(Bbase + (size_t)r * 128 + cb);
            }
        }
    };

    for (int t = 0; t < NT; t++) {
        const int cur = t & 1;
        const char* Abase = (const char*)&As[cur][0][0];
        const char* Bbase = (const char*)&Bs[cur][0][0];
        const bool pf = (t + 2 < NT);
        const int kn = (t + 2) * BK;

        load_af8(Abase, 0);
        load_bf4(Bbase, 0, bfv0);
        __builtin_amdgcn_s_barrier();
        __builtin_amdgcn_s_setprio(1);
#pragma unroll
        for (int kk = 0; kk < 2; kk++)
#pragma unroll
            for (int fi = 0; fi < 4; fi++)
#pragma unroll
                for (int fj = 0; fj < 2; fj++)
                    acc[0][0][fi][fj] = __builtin_amdgcn_mfma_f32_16x16x32_bf16(
                        af[fi][kk], bfv0[fj][kk], acc[0][0][fi][fj], 0, 0, 0);
        __builtin_amdgcn_s_setprio(0);
        __builtin_amdgcn_s_barrier();

        load_bf4(Bbase, 1, bfv1);
        if (pf) stage_half(cur, 0, kn);
        __builtin_amdgcn_s_barrier();
        __builtin_amdgcn_s_setprio(1);
#pragma unroll
        for (int kk = 0; kk < 2; kk++)
#pragma unroll
            for (int fi = 0; fi < 4; fi++)
#pragma unroll
                for (int fj = 0; fj < 2; fj++)
                    acc[0][1][fi][fj] = __builtin_amdgcn_mfma_f32_16x16x32_bf16(
                        af[fi][kk], bfv1[fj][kk], acc[0][1][fi][fj], 0, 0, 0);
        __builtin_amdgcn_s_setprio(0);
        __builtin_amdgcn_s_barrier();

        load_af8(Abase, 1);
        if (pf) stage_half(cur, 1, kn);
        __builtin_amdgcn_s_barrier();
        __builtin_amdgcn_s_setprio(1);
#pragma unroll
        for (int kk = 0; kk < 2; kk++)
#pragma unroll
            for (int fi = 0; fi < 4; fi++)
#pragma unroll
                for (int fj = 0; fj < 2; fj++)
                    acc[1][1][fi][fj] = __builtin_amdgcn_mfma_f32_16x16x32_bf16(
                        af[fi][kk], bfv1[fj][kk], acc[1][1][fi][fj], 0, 0, 0);
        __builtin_amdgcn_s_setprio(0);
        __builtin_amdgcn_s_barrier();

        if (pf) { stage_half(cur, 2, kn); stage_half(cur, 3, kn); }
        __builtin_amdgcn_s_barrier();
        __builtin_amdgcn_s_setprio(1);
#pragma unroll
        for (int kk = 0; kk < 2; kk++)
#pragma unroll
            for (int fi = 0; fi < 4; fi++)
#pragma unroll
                for (int fj = 0; fj < 2; fj++)
                    acc[1][0][fi][fj] = __builtin_amdgcn_mfma_f32_16x16x32_bf16(
                        af[fi][kk], bfv0[fj][kk], acc[1][0][fi][fj], 0, 0, 0);
        __builtin_amdgcn_s_setprio(0);
        if (t == NT - 2) asm volatile("s_waitcnt vmcnt(0)" ::: "memory");
        else             asm volatile("s_waitcnt vmcnt(8)" ::: "memory");
        __builtin_amdgcn_s_barrier();
        asm volatile("" ::: "memory");
    }

#pragma unroll
    for (int mh = 0; mh < 2; mh++)
#pragma unroll
        for (int nh = 0; nh < 2; nh++)
#pragma unroll
            for (int fi = 0; fi < 4; fi++)
#pragma unroll
                for (int fj = 0; fj < 2; fj++)
#pragma unroll
                    for (int r = 0; r < 4; r++) {
                        int row = im * 256 + mh * 128 + wm * 64 + fi * 16 + lq * 4 + r;
                        int col = in * 256 + nh * 128 + wn * 32 + fj * 16 + lr;
                        epi_store<EPI>(acc[mh][nh][fi][fj][r], row, col, Cv, ldc, bias);
                    }
}

// ---------- 128xBN weight GEMM (QKV / proj / FC / FC2) ----------
template <int BM, int BN, int BK, int EPI, bool SWZG>
__global__ __launch_bounds__(256) void gemm_fast(
    const bf16* __restrict__ A, int lda,
    const bf16* __restrict__ Bm, int ldb,
    void* __restrict__ Cv, int ldc,
    const float* __restrict__ bias, int K)
{
    static_assert(BK == 64, "staging geometry assumes BK=64");
    __shared__ alignas(16) bf16 As[2][BM][BK];
    __shared__ alignas(16) bf16 Bs[2][BN][BK];

    const int tid = threadIdx.x;
    const int lane = tid & 63;
    const int w = tid >> 6;
    const int wm = w >> 1, wn = w & 1;
    constexpr int WM = BM / 2, WN = BN / 2;
    constexpr int FM = WM / 16, FN = WN / 16;
    constexpr int RPI = 512 / BK;
    constexpr int AI = BM / (4 * RPI);
    constexpr int BI = BN / (4 * RPI);

    int im, in;
    if constexpr (SWZG) {
        int nwg = gridDim.x * gridDim.y;
        int orig = blockIdx.y * gridDim.x + blockIdx.x;
        int q = nwg >> 3, rr = nwg & 7, xcd = orig & 7, lid = orig >> 3;
        int wg = (xcd < rr ? xcd * (q + 1) : rr * (q + 1) + (xcd - rr) * q) + lid;
        im = wg % gridDim.x;
        in = wg / gridDim.x;
    } else {
        im = blockIdx.y;
        in = blockIdx.x;
    }

    const bf16* Ab = A + (size_t)im * BM * lda;
    const bf16* Bb = Bm + (size_t)in * BN * ldb;

    const int sr = lane >> 3;
    const int scs = (((lane & 7) ^ sr) * 8);
    const int lr = lane & 15, lq = lane >> 4;

    f32x4 acc[FM][FN];
#pragma unroll
    for (int i = 0; i < FM; i++)
#pragma unroll
        for (int j = 0; j < FN; j++) acc[i][j] = (f32x4){0.f, 0.f, 0.f, 0.f};

    auto stage = [&](int buf, int k0) {
#pragma unroll
        for (int i = 0; i < AI; i++) {
            int row = (w * AI + i) * RPI;
            gl2lds16(Ab + (size_t)(row + sr) * lda + k0 + scs, &As[buf][row][0]);
        }
#pragma unroll
        for (int i = 0; i < BI; i++) {
            int row = (w * BI + i) * RPI;
            gl2lds16(Bb + (size_t)(row + sr) * ldb + k0 + scs, &Bs[buf][row][0]);
        }
    };

    const int NT = K / BK;
    stage(0, 0);
    __syncthreads();

    for (int t = 0; t < NT; t++) {
        const int cur = t & 1;
        if (t + 1 < NT) stage(cur ^ 1, (t + 1) * BK);

        const char* Abase = (const char*)&As[cur][0][0];
        const char* Bbase = (const char*)&Bs[cur][0][0];
#pragma unroll
        for (int kk = 0; kk < BK / 32; kk++) {
            short8 af[FM], bfr[FN];
#pragma unroll
            for (int i = 0; i < FM; i++) {
                int r = wm * WM + i * 16 + lr;
                int cb = (kk * 64 + lq * 16) ^ ((r & 7) << 4);
                af[i] = *reinterpret_cast<const short8*>(Abase + (size_t)r * (BK * 2) + cb);
            }
#pragma unroll
            for (int j = 0; j < FN; j++) {
                int r = wn * WN + j * 16 + lr;
                int cb = (kk * 64 + lq * 16) ^ ((r & 7) << 4);
                bfr[j] = *reinterpret_cast<const short8*>(Bbase + (size_t)r * (BK * 2) + cb);
            }
#pragma unroll
            for (int i = 0; i < FM; i++)
#pragma unroll
                for (int j = 0; j < FN; j++)
                    acc[i][j] = __builtin_amdgcn_mfma_f32_16x16x32_bf16(af[i], bfr[j], acc[i][j], 0, 0, 0);
        }
        __syncthreads();
    }

#pragma unroll
    for (int i = 0; i < FM; i++)
#pragma unroll
        for (int j = 0; j < FN; j++)
#pragma unroll
            for (int r = 0; r < 4; r++) {
                int row = im * BM + wm * WM + i * 16 + lq * 4 + r;
                int col = in * BN + wn * WN + j * 16 + lr;
                epi_store<EPI>(acc[i][j][r], row, col, Cv, ldc, bias);
            }
}

// ---------- slow lm_head fallback (B fp32) ----------
template <int BM, int BN, int BK, int EPI>
__global__ __launch_bounds__(256) void gemm_bt_f32(
    const bf16* __restrict__ A, int lda,
    const float* __restrict__ Bm, int ldb,
    void* __restrict__ Cv, int ldc,
    const float* __restrict__ bias, int K)
{
    constexpr int BKP = BK + 8;
    __shared__ bf16 As[BM][BKP];
    __shared__ bf16 Bs[BN][BKP];
    const int tid = threadIdx.x;
    const int lane = tid & 63;
    const int w = tid >> 6;
    const int wm = w >> 1, wn = w & 1;
    constexpr int WM = BM / 2, WN = BN / 2;
    constexpr int FM = WM / 16, FN = WN / 16;
    const int bx = blockIdx.x, by = blockIdx.y;
    const bf16* Ab = A + (size_t)by * BM * lda;
    const float* Bb = Bm + (size_t)bx * BN * ldb;
    f32x4 acc[FM][FN];
#pragma unroll
    for (int i = 0; i < FM; i++)
#pragma unroll
        for (int j = 0; j < FN; j++) acc[i][j] = (f32x4){0.f, 0.f, 0.f, 0.f};
    const int lr = lane & 15, lq = lane >> 4;
    for (int k0 = 0; k0 < K; k0 += BK) {
        constexpr int AC = (BM * BK) / (256 * 8);
#pragma unroll
        for (int i = 0; i < AC; i++) {
            int c = tid + i * 256;
            int row = c / (BK / 8);
            int kc = (c % (BK / 8)) * 8;
            *reinterpret_cast<int4*>(&As[row][kc]) =
                *reinterpret_cast<const int4*>(Ab + (size_t)row * lda + k0 + kc);
        }
        constexpr int BC = (BN * BK) / (256 * 4);
#pragma unroll
        for (int i = 0; i < BC; i++) {
            int c = tid + i * 256;
            int row = c / (BK / 4);
            int kc = (c % (BK / 4)) * 4;
            float4 v = *reinterpret_cast<const float4*>(Bb + (size_t)row * ldb + k0 + kc);
            unsigned long long p = (unsigned long long)f2bu(v.x) |
                                   ((unsigned long long)f2bu(v.y) << 16) |
                                   ((unsigned long long)f2bu(v.z) << 32) |
                                   ((unsigned long long)f2bu(v.w) << 48);
            *reinterpret_cast<unsigned long long*>(&Bs[row][kc]) = p;
        }
        __syncthreads();
#pragma unroll
        for (int kk = 0; kk < BK / 32; kk++) {
            short8 af[FM], bfr[FN];
#pragma unroll
            for (int i = 0; i < FM; i++)
                af[i] = *reinterpret_cast<const short8*>(&As[wm * WM + i * 16 + lr][kk * 32 + lq * 8]);
#pragma unroll
            for (int j = 0; j < FN; j++)
                bfr[j] = *reinterpret_cast<const short8*>(&Bs[wn * WN + j * 16 + lr][kk * 32 + lq * 8]);
#pragma unroll
            for (int i = 0; i < FM; i++)
#pragma unroll
                for (int j = 0; j < FN; j++)
                    acc[i][j] = __builtin_amdgcn_mfma_f32_16x16x32_bf16(af[i], bfr[j], acc[i][j], 0, 0, 0);
        }
        __syncthreads();
    }
#pragma unroll
    for (int i = 0; i < FM; i++)
#pragma unroll
        for (int j = 0; j < FN; j++)
#pragma unroll
            for (int r = 0; r < 4; r++) {
                int row = by * BM + wm * WM + i * 16 + lq * 4 + r;
                int col = bx * BN + wn * WN + j * 16 + lr;
                epi_store<EPI>(acc[i][j][r], row, col, Cv, ldc, bias);
            }
}

// ---------- flash attention: single-buffered + XCD-chunked z-grouping ----------
__global__ __launch_bounds__(256) void flash_attn(
    const bf16* __restrict__ q, const bf16* __restrict__ kbuf,
    const bf16* __restrict__ vt, bf16* __restrict__ y)
{
    __shared__ alignas(16) bf16 Ks[128 * 64];
    __shared__ alignas(16) bf16 Vs[64 * 128];
    __shared__ alignas(16) bf16 Ps[4 * 16 * 136];

    const int tid = threadIdx.x;
    const int lane = tid & 63;
    const int w = tid >> 6;
    const int lr = lane & 15, lq = lane >> 4;

    int flat = blockIdx.y * gridDim.x + blockIdx.x;
    int xcd = flat & 7, lid = flat >> 3;
    int wg = xcd * 64 + lid;
    const int z = wg >> 4;
    const int qi = 15 - (wg & 15);
    const int b = z >> 4, h = z & 15;
    const float slope = exp2f(-0.5f * (float)(h + 1));

    const bf16* qz = q + (size_t)z * (Tc * HDc);
    const bf16* kz = kbuf + (size_t)z * (Tc * HDc);
    const bf16* vz = vt + (size_t)z * (HDc * Tc);

    const int rowbase = qi * 64 + w * 16;

    short8 qf[2];
#pragma unroll
    for (int kk = 0; kk < 2; kk++)
        qf[kk] = *reinterpret_cast<const short8*>(
            qz + (size_t)(rowbase + lr) * HDc + kk * 32 + lq * 8);

    float m_old[4], l_sum[4];
#pragma unroll
    for (int r = 0; r < 4; r++) { m_old[r] = -3.0e38f; l_sum[r] = 0.f; }
    f32x4 o[4];
#pragma unroll
    for (int dj = 0; dj < 4; dj++) o[dj] = (f32x4){0.f, 0.f, 0.f, 0.f};

    bf16* Pw = Ps + w * 16 * 136;

    const int nkv = (qi * 64 + 63) / 128 + 1;
    for (int kv = 0; kv < nkv; kv++) {
#pragma unroll
        for (int i = 0; i < 4; i++) {
            int rbase = w * 32 + i * 8;
            int row = rbase + (lane >> 3);
            int slot = lane & 7;
            gl2lds16(kz + (size_t)(kv * 128 + row) * HDc + ((slot ^ (row & 7)) * 8),
                     &Ks[rbase * 64]);
        }
#pragma unroll
        for (int i = 0; i < 4; i++) {
            int rbase = w * 16 + i * 4;
            int row = rbase + lq;
            gl2lds16(vz + (size_t)row * Tc + kv * 128 + ((lr ^ (row & 7)) * 8),
                     &Vs[rbase * 128]);
        }
        __syncthreads();

        f32x4 s[8];
#pragma unroll
        for (int j = 0; j < 8; j++) s[j] = (f32x4){0.f, 0.f, 0.f, 0.f};
#pragma unroll
        for (int kk = 0; kk < 2; kk++) {
#pragma unroll
            for (int j = 0; j < 8; j++) {
                int row = j * 16 + lr;
                int cb = ((kk * 4 + lq) ^ (row & 7)) << 4;
                short8 bfr = *reinterpret_cast<const short8*>(
                    (const char*)Ks + row * 128 + cb);
                s[j] = __builtin_amdgcn_mfma_f32_16x16x32_bf16(qf[kk], bfr, s[j], 0, 0, 0);
            }
        }

        float mt[4];
#pragma unroll
        for (int r = 0; r < 4; r++) mt[r] = -3.0e38f;
#pragma unroll
        for (int j = 0; j < 8; j++) {
            int col = kv * 128 + j * 16 + lr;
#pragma unroll
            for (int r = 0; r < 4; r++) {
                int rowg = rowbase + lq * 4 + r;
                float v = s[j][r] * 0.125f - (float)(rowg - col) * slope;
                v = (col > rowg) ? -3.0e38f : v;
                s[j][r] = v;
                mt[r] = fmaxf(mt[r], v);
            }
        }
#pragma unroll
        for (int r = 0; r < 4; r++)
#pragma unroll
            for (int off = 1; off < 16; off <<= 1)
                mt[r] = fmaxf(mt[r], __shfl_xor(mt[r], off));

        float f[4], rs[4];
#pragma unroll
        for (int r = 0; r < 4; r++) {
            float mn = fmaxf(m_old[r], mt[r]);
            f[r] = __expf(m_old[r] - mn);
            m_old[r] = mn;
            rs[r] = 0.f;
        }
#pragma unroll
        for (int j = 0; j < 8; j++)
#pragma unroll
            for (int r = 0; r < 4; r++) {
                float p = __expf(s[j][r] - m_old[r]);
                s[j][r] = p;
                rs[r] += p;
            }
#pragma unroll
        for (int r = 0; r < 4; r++) {
#pragma unroll
            for (int off = 1; off < 16; off <<= 1)
                rs[r] += __shfl_xor(rs[r], off);
            l_sum[r] = l_sum[r] * f[r] + rs[r];
        }

#pragma unroll
        for (int j = 0; j < 8; j++)
#pragma unroll
            for (int r = 0; r < 4; r++)
                Pw[(lq * 4 + r) * 136 + j * 16 + lr] = __float2bfloat16(s[j][r]);

#pragma unroll
        for (int dj = 0; dj < 4; dj++)
#pragma unroll
            for (int r = 0; r < 4; r++) o[dj][r] *= f[r];

        __syncthreads();

#pragma unroll
        for (int kk = 0; kk < 4; kk++) {
            short8 pa = *reinterpret_cast<const short8*>(
                (const char*)Pw + lr * 272 + kk * 64 + lq * 16);
#pragma unroll
            for (int dj = 0; dj < 4; dj++) {
                int row = dj * 16 + lr;
                int cb = ((kk * 4 + lq) ^ (row & 7)) << 4;
                short8 vb = *reinterpret_cast<const short8*>(
                    (const char*)Vs + row * 256 + cb);
                o[dj] = __builtin_amdgcn_mfma_f32_16x16x32_bf16(pa, vb, o[dj], 0, 0, 0);
            }
        }
        __syncthreads();
    }

#pragma unroll
    for (int dj = 0; dj < 4; dj++)
#pragma unroll
        for (int r = 0; r < 4; r++) {
            int rowg = rowbase + lq * 4 + r;
            float outv = o[dj][r] / l_sum[r];
            y[((size_t)b * Tc + rowg) * Dc + h * HDc + dj * 16 + lr] =
                __float2bfloat16(outv);
        }
}

// ---------- fused weight conversion ----------
constexpr long C_AW = 1572864;
constexpr long C_PW = C_AW + 524288;
constexpr long C_FW = C_PW + 2097152;
constexpr long C_F2 = C_FW + 2097152;
constexpr long C_LM = C_F2 + 4096000;

__device__ __forceinline__ void cvt8(const float* src, bf16* dst) {
    float4 a = *reinterpret_cast<const float4*>(src);
    float4 b = *reinterpret_cast<const float4*>(src + 4);
    unsigned long long p0 = (unsigned long long)f2bu(a.x) |
                            ((unsigned long long)f2bu(a.y) << 16) |
                            ((unsigned long long)f2bu(a.z) << 32) |
                            ((unsigned long long)f2bu(a.w) << 48);
    unsigned long long p1 = (unsigned long long)f2bu(b.x) |
                            ((unsigned long long)f2bu(b.y) << 16) |
                            ((unsigned long long)f2bu(b.z) << 32) |
                            ((unsigned long long)f2bu(b.w) << 48);
    *reinterpret_cast<unsigned long long*>(dst) = p0;
    *reinterpret_cast<unsigned long long*>(dst + 4) = p1;
}

__global__ __launch_bounds__(256) void f2b8_multi(
    const float* aw, bf16* awb, const float* pw, bf16* pwb,
    const float* fw, bf16* fwb, const float* f2, bf16* f2b,
    const float* lm, bf16* lmb, long total) {
    long i = (long)blockIdx.x * 256 + threadIdx.x;
    if (i >= total) return;
    if (i < C_AW)      cvt8(aw + i * 8, awb + i * 8);
    else if (i < C_PW) { long j = i - C_AW; cvt8(pw + j * 8, pwb + j * 8); }
    else if (i < C_FW) { long j = i - C_PW; cvt8(fw + j * 8, fwb + j * 8); }
    else if (i < C_F2) { long j = i - C_FW; cvt8(f2 + j * 8, f2b + j * 8); }
    else               { long j = i - C_F2; cvt8(lm + j * 8, lmb + j * 8); }
}

__global__ __launch_bounds__(256) void embed_kernel(const int* __restrict__ ids,
                                                    const float* __restrict__ wte,
                                                    bf16* __restrict__ x) {
    int row = blockIdx.x;
    int t = threadIdx.x;
    int id = ids[row];
    float4 v = reinterpret_cast<const float4*>(wte + (size_t)id * Dc)[t];
    unsigned long long p = (unsigned long long)f2bu(v.x) |
                           ((unsigned long long)f2bu(v.y) << 16) |
                           ((unsigned long long)f2bu(v.z) << 32) |
                           ((unsigned long long)f2bu(v.w) << 48);
    *reinterpret_cast<unsigned long long*>(x + (size_t)row * Dc + t * 4) = p;
}

__global__ __launch_bounds__(256) void ln_kernel(const bf16* __restrict__ x,
                                                 const float* __restrict__ g,
                                                 const float* __restrict__ b,
                                                 bf16* __restrict__ out) {
    int row = blockIdx.x;
    int t = threadIdx.x;
    unsigned long long uv = *reinterpret_cast<const unsigned long long*>(
        x + (size_t)row * Dc + t * 4);
    float vv[4];
#pragma unroll
    for (int j = 0; j < 4; j++) vv[j] = bu2f((unsigned short)(uv >> (16 * j)));
    float s = vv[0] + vv[1] + vv[2] + vv[3];
    float s2 = vv[0] * vv[0] + vv[1] * vv[1] + vv[2] * vv[2] + vv[3] * vv[3];
#pragma unroll
    for (int o = 32; o > 0; o >>= 1) {
        s += __shfl_down(s, o);
        s2 += __shfl_down(s2, o);
    }
    __shared__ float sm[8];
    int wid = t >> 6, ln = t & 63;
    if (ln == 0) { sm[wid] = s; sm[4 + wid] = s2; }
    __syncthreads();
    if (t == 0) {
        float ts = sm[0] + sm[1] + sm[2] + sm[3];
        float ts2 = sm[4] + sm[5] + sm[6] + sm[7];
        sm[0] = ts; sm[4] = ts2;
    }
    __syncthreads();
    float mean = sm[0] * (1.0f / Dc);
    float var = sm[4] * (1.0f / Dc) - mean * mean;
    float rstd = rsqrtf(var + 1e-5f);
    int c0 = t * 4;
    unsigned long long p = 0;
#pragma unroll
    for (int j = 0; j < 4; j++) {
        float val = (vv[j] - mean) * rstd * g[c0 + j] + b[c0 + j];
        p |= (unsigned long long)f2bu(val) << (16 * j);
    }
    *reinterpret_cast<unsigned long long*>(out + (size_t)row * Dc + c0) = p;
}

__global__ __launch_bounds__(256) void v2vt(const bf16* __restrict__ v,
                                            bf16* __restrict__ vt) {
    int idx = blockIdx.x * 256 + threadIdx.x;
    int tc = idx & 127;
    int t0 = tc * 8;
    int rest = idx >> 7;
    int hd = rest & 63;
    int z = rest >> 6;
    const bf16* src = v + ((size_t)z * Tc) * HDc + hd;
    unsigned long long p0 = 0, p1 = 0;
#pragma unroll
    for (int i = 0; i < 4; i++) {
        unsigned short u;
        __builtin_memcpy(&u, src + (size_t)(t0 + i) * HDc, 2);
        p0 |= (unsigned long long)u << (16 * i);
    }
#pragma unroll
    for (int i = 0; i < 4; i++) {
        unsigned short u;
        __builtin_memcpy(&u, src + (size_t)(t0 + 4 + i) * HDc, 2);
        p1 |= (unsigned long long)u << (16 * i);
    }
    bf16* dst = vt + ((size_t)z * HDc + hd) * Tc + t0;
    *reinterpret_cast<unsigned long long*>(dst) = p0;
    *reinterpret_cast<unsigned long long*>(dst + 4) = p1;
}

extern "C" void kernel_launch(void* const* d_in, const int* in_sizes, int n_in,
                              void* d_out, int out_size, void* d_ws, size_t ws_size,
                              hipStream_t stream) {
    const int* ids = (const int*)d_in[0];
    const float* wte = (const float*)d_in[1];
    const float* ln1g = (const float*)d_in[2];
    const float* ln1b = (const float*)d_in[3];
    const float* attw = (const float*)d_in[4];
    const float* attb = (const float*)d_in[5];
    const float* projw = (const float*)d_in[6];
    const float* projb = (const float*)d_in[7];
    const float* ln2g = (const float*)d_in[8];
    const float* ln2b = (const float*)d_in[9];
    const float* fcw = (const float*)d_in[10];
    const float* fcb = (const float*)d_in[11];
    const float* fc2w = (const float*)d_in[12];
    const float* fc2b = (const float*)d_in[13];
    const float* lnfg = (const float*)d_in[14];
    const float* lnfb = (const float*)d_in[15];
    const float* lmw = (const float*)d_in[16];

    const int M = Bc * Tc;  // 2048
    char* ws = (char*)d_ws;
    size_t off = 0;
    auto carve = [&](size_t bytes) { char* p = ws + off; off += (bytes + 255) & ~(size_t)255; return p; };

    bf16* x = (bf16*)carve((size_t)M * Dc * 2);
    bf16* h = (bf16*)carve((size_t)M * Dc * 2);
    bf16* qkvb = (bf16*)carve((size_t)3 * 2097152 * 2);
    bf16* vt = (bf16*)carve((size_t)Bc * Hc * HDc * Tc * 2);
    bf16* y = (bf16*)carve((size_t)M * Dc * 2);
    bf16* mlp = (bf16*)carve((size_t)M * MLPc * 2);
    bf16* q = qkvb;
    bf16* kb = qkvb + 2097152;
    bf16* vtmp = qkvb + 4194304;

    const long nLM = (long)Vc * Dc;
    bool has_wlm = ws_size >= off + (size_t)nLM * 2;
    bf16* wlm = nullptr;
    if (has_wlm) wlm = (bf16*)carve((size_t)nLM * 2);

    const long nAW = (long)Lc * 3 * Dc * Dc;
    const long nPW = (long)Lc * Dc * Dc;
    const long nFW = (long)Lc * MLPc * Dc;
    const long nF2W = (long)Lc * Dc * MLPc;
    bf16* awAll = (bf16*)d_out;
    bf16* pwAll = awAll + nAW;
    bf16* fwAll = pwAll + nPW;
    bf16* f2wAll = fwAll + nFW;

    embed_kernel<<<M, 256, 0, stream>>>(ids, wte, x);

    const long totChunks = has_wlm ? C_LM : C_F2;
    f2b8_multi<<<(int)((totChunks + 255) / 256), 256, 0, stream>>>(
        attw, awAll, projw, pwAll, fcw, fwAll, fc2w, f2wAll,
        lmw, wlm, totChunks);

    for (int l = 0; l < Lc; l++) {
        bf16* aw_b = awAll + (size_t)l * 3 * Dc * Dc;
        bf16* pw_b = pwAll + (size_t)l * Dc * Dc;
        bf16* fw_b = fwAll + (size_t)l * MLPc * Dc;
        bf16* f2w_b = f2wAll + (size_t)l * Dc * MLPc;

        ln_kernel<<<M, 256, 0, stream>>>(x, ln1g + l * Dc, ln1b + l * Dc, h);

        gemm_fast<128, 64, 64, EPI_QKV, true>
            <<<dim3(M / 128, 3 * Dc / 64, 1), 256, 0, stream>>>(
                h, Dc, aw_b, Dc, qkvb, 0, attb + l * 3 * Dc, Dc);

        v2vt<<<(Bc * Hc * HDc * (Tc / 8)) / 256, 256, 0, stream>>>(vtmp, vt);

        flash_attn<<<dim3(Tc / 64, Bc * Hc), 256, 0, stream>>>(q, kb, vt, y);

        gemm_fast<128, 64, 64, EPI_RESADD, true>
            <<<dim3(M / 128, Dc / 64, 1), 256, 0, stream>>>(
                y, Dc, pw_b, Dc, x, Dc, projb + l * Dc, Dc);

        ln_kernel<<<M, 256, 0, stream>>>(x, ln2g + l * Dc, ln2b + l * Dc, h);

        gemm_fast<128, 128, 64, EPI_GELU, true>
            <<<dim3(M / 128, MLPc / 128, 1), 256, 0, stream>>>(
                h, Dc, fw_b, Dc, mlp, MLPc, fcb + l * MLPc, Dc);

        gemm_fast<128, 64, 64, EPI_RESADD, true>
            <<<dim3(M / 128, Dc / 64, 1), 256, 0, stream>>>(
                mlp, MLPc, f2w_b, MLPc, x, Dc, fc2b + l * Dc, MLPc);
    }

    ln_kernel<<<M, 256, 0, stream>>>(x, lnfg, lnfb, h);

    if (has_wlm)
        gemm_8p<EPI_F32>
            <<<dim3(M / 256, Vc / 256, 1), 512, 0, stream>>>(
                h, Dc, wlm, Dc, (float*)d_out, Vc, nullptr, Dc);
    else
        gemm_bt_f32<128, 128, 64, EPI_F32>
            <<<dim3(Vc / 128, M / 128, 1), 256, 0, stream>>>(
                h, Dc, lmw, Dc, (float*)d_out, Vc, nullptr, Dc);
}

// Round 19
// 1099.011 us; speedup vs baseline: 1.0127x; 1.0127x over previous
//
#include <hip/hip_runtime.h>
#include <hip/hip_bf16.h>
#include <math.h>

typedef __hip_bfloat16 bf16;
typedef __attribute__((ext_vector_type(4))) float f32x4;
typedef __attribute__((ext_vector_type(8))) short short8;

constexpr int Bc = 2, Tc = 1024, Dc = 1024, Hc = 16, Lc = 4, MLPc = 4096, Vc = 32000, HDc = 64;

__device__ __forceinline__ unsigned short f2bu(float f) {
    __hip_bfloat16 h = __float2bfloat16(f);
    unsigned short u;
    __builtin_memcpy(&u, &h, 2);
    return u;
}
__device__ __forceinline__ float bu2f(unsigned short u) {
    __hip_bfloat16 h;
    __builtin_memcpy(&h, &u, 2);
    return __bfloat162float(h);
}

__device__ __forceinline__ void gl2lds16(const bf16* g, bf16* l) {
    __builtin_amdgcn_global_load_lds(
        (const __attribute__((address_space(1))) void*)g,
        (__attribute__((address_space(3))) void*)l, 16, 0, 0);
}

enum { EPI_BIAS_BF16 = 0, EPI_GELU = 1, EPI_RESADD = 2, EPI_F32 = 3, EPI_QKV = 4 };

template <int EPI>
__device__ __forceinline__ void epi_store(float v, int row, int col, void* Cv,
                                          int ldc, const float* bias) {
    if constexpr (EPI == EPI_BIAS_BF16) {
        v += bias[col];
        ((bf16*)Cv)[(size_t)row * ldc + col] = __float2bfloat16(v);
    } else if constexpr (EPI == EPI_GELU) {
        v += bias[col];
        v = 0.5f * v * (1.0f + erff(v * 0.70710678118f));
        ((bf16*)Cv)[(size_t)row * ldc + col] = __float2bfloat16(v);
    } else if constexpr (EPI == EPI_RESADD) {
        bf16* C = (bf16*)Cv;
        size_t idx = (size_t)row * ldc + col;
        float xo = __bfloat162float(C[idx]);
        C[idx] = __float2bfloat16(xo + v + bias[col]);
    } else if constexpr (EPI == EPI_F32) {
        ((float*)Cv)[(size_t)row * ldc + col] = v;
    } else if constexpr (EPI == EPI_QKV) {
        v += bias[col];
        bf16 bv = __float2bfloat16(v);
        int b = row >> 10, t = row & 1023;
        int seg = col >> 10;
        int cc = col & 1023;
        int h = cc >> 6, hd = cc & 63;
        bf16* base = (bf16*)Cv;
        base[(size_t)seg * 2097152 + ((size_t)(b * Hc + h) * Tc + t) * HDc + hd] = bv;
    }
}

// ---------- 256x256 GEMM, m201-faithful pipeline (lm_head) ----------
template <int EPI>
__global__ __launch_bounds__(512) void gemm_8p(
    const bf16* __restrict__ A, int lda,
    const bf16* __restrict__ Bm, int ldb,
    void* __restrict__ Cv, int ldc,
    const float* __restrict__ bias, int K)
{
    constexpr int BM = 256, BN = 256, BK = 64;
    __shared__ alignas(16) bf16 As[2][BM][BK];
    __shared__ alignas(16) bf16 Bs[2][BN][BK];

    const int tid = threadIdx.x;
    const int lane = tid & 63;
    const int w = tid >> 6;
    const int wm = w >> 2;
    const int wn = w & 3;

    int nwg = gridDim.x * gridDim.y;
    int orig = blockIdx.y * gridDim.x + blockIdx.x;
    int q = nwg >> 3, rr = nwg & 7, xcd = orig & 7, lid = orig >> 3;
    int wg = (xcd < rr ? xcd * (q + 1) : rr * (q + 1) + (xcd - rr) * q) + lid;
    int im = wg % gridDim.x;
    int in = wg / gridDim.x;

    const bf16* Ab = A + (size_t)im * BM * lda;
    const bf16* Bb = Bm + (size_t)in * BN * ldb;

    const int sr = lane >> 3;
    const int scs = ((lane & 7) ^ sr) * 8;
    const int lr = lane & 15, lq = lane >> 4;

    f32x4 acc[2][2][4][2];
#pragma unroll
    for (int a = 0; a < 2; a++)
#pragma unroll
        for (int b = 0; b < 2; b++)
#pragma unroll
            for (int c = 0; c < 4; c++)
#pragma unroll
                for (int d = 0; d < 2; d++) acc[a][b][c][d] = (f32x4){0.f, 0.f, 0.f, 0.f};

    const int NT = K / BK;

    auto stage_half = [&](int buf, int sg, int k0) {
        const bool isB = (sg == 1 || sg == 2);
        const bf16* gp = isB ? Bb : Ab;
        const int ld = isB ? ldb : lda;
        bf16* ls = isB ? &Bs[buf][0][0] : &As[buf][0][0];
        const int half = (sg == 2 || sg == 3) ? 1 : 0;
#pragma unroll
        for (int i = 0; i < 2; i++) {
            int r0 = half * 128 + i * 64 + w * 8;
            gl2lds16(gp + (size_t)(r0 + sr) * ld + k0 + scs, ls + r0 * BK);
        }
    };

#pragma unroll
    for (int sg = 0; sg < 4; sg++) stage_half(0, sg, 0);
#pragma unroll
    for (int sg = 0; sg < 4; sg++) stage_half(1, sg, BK);
    asm volatile("s_waitcnt vmcnt(8)" ::: "memory");
    __builtin_amdgcn_s_barrier();
    asm volatile("" ::: "memory");

    short8 af[4][2], bfv0[2][2], bfv1[2][2];

    auto load_af8 = [&](const char* Abase, int mh) {
#pragma unroll
        for (int fi = 0; fi < 4; fi++) {
            int r = mh * 128 + wm * 64 + fi * 16 + lr;
#pragma unroll
            for (int kk = 0; kk < 2; kk++) {
                int cb = (kk * 64 + lq * 16) ^ ((r & 7) << 4);
                af[fi][kk] = *reinterpret_cast<const short8*>(Abase + (size_t)r * 128 + cb);
            }
        }
    };
    auto load_bf4 = [&](const char* Bbase, int nh, short8 (&bfv)[2][2]) {
#pragma unroll
        for (int fj = 0; fj < 2; fj++) {
            int r = nh * 128 + wn * 32 + fj * 16 + lr;
#pragma unroll
            for (int kk = 0; kk < 2; kk++) {
                int cb = (kk * 64 + lq * 16) ^ ((r & 7) << 4);
                bfv[fj][kk] = *reinterpret_cast<const short8*>(Bbase + (size_t)r * 128 + cb);
            }
        }
    };

    for (int t = 0; t < NT; t++) {
        const int cur = t & 1;
        const char* Abase = (const char*)&As[cur][0][0];
        const char* Bbase = (const char*)&Bs[cur][0][0];
        const bool pf = (t + 2 < NT);
        const int kn = (t + 2) * BK;

        load_af8(Abase, 0);
        load_bf4(Bbase, 0, bfv0);
        __builtin_amdgcn_s_barrier();
        __builtin_amdgcn_s_setprio(1);
#pragma unroll
        for (int kk = 0; kk < 2; kk++)
#pragma unroll
            for (int fi = 0; fi < 4; fi++)
#pragma unroll
                for (int fj = 0; fj < 2; fj++)
                    acc[0][0][fi][fj] = __builtin_amdgcn_mfma_f32_16x16x32_bf16(
                        af[fi][kk], bfv0[fj][kk], acc[0][0][fi][fj], 0, 0, 0);
        __builtin_amdgcn_s_setprio(0);
        __builtin_amdgcn_s_barrier();

        load_bf4(Bbase, 1, bfv1);
        if (pf) stage_half(cur, 0, kn);
        __builtin_amdgcn_s_barrier();
        __builtin_amdgcn_s_setprio(1);
#pragma unroll
        for (int kk = 0; kk < 2; kk++)
#pragma unroll
            for (int fi = 0; fi < 4; fi++)
#pragma unroll
                for (int fj = 0; fj < 2; fj++)
                    acc[0][1][fi][fj] = __builtin_amdgcn_mfma_f32_16x16x32_bf16(
                        af[fi][kk], bfv1[fj][kk], acc[0][1][fi][fj], 0, 0, 0);
        __builtin_amdgcn_s_setprio(0);
        __builtin_amdgcn_s_barrier();

        load_af8(Abase, 1);
        if (pf) stage_half(cur, 1, kn);
        __builtin_amdgcn_s_barrier();
        __builtin_amdgcn_s_setprio(1);
#pragma unroll
        for (int kk = 0; kk < 2; kk++)
#pragma unroll
            for (int fi = 0; fi < 4; fi++)
#pragma unroll
                for (int fj = 0; fj < 2; fj++)
                    acc[1][1][fi][fj] = __builtin_amdgcn_mfma_f32_16x16x32_bf16(
                        af[fi][kk], bfv1[fj][kk], acc[1][1][fi][fj], 0, 0, 0);
        __builtin_amdgcn_s_setprio(0);
        __builtin_amdgcn_s_barrier();

        if (pf) { stage_half(cur, 2, kn); stage_half(cur, 3, kn); }
        __builtin_amdgcn_s_barrier();
        __builtin_amdgcn_s_setprio(1);
#pragma unroll
        for (int kk = 0; kk < 2; kk++)
#pragma unroll
            for (int fi = 0; fi < 4; fi++)
#pragma unroll
                for (int fj = 0; fj < 2; fj++)
                    acc[1][0][fi][fj] = __builtin_amdgcn_mfma_f32_16x16x32_bf16(
                        af[fi][kk], bfv0[fj][kk], acc[1][0][fi][fj], 0, 0, 0);
        __builtin_amdgcn_s_setprio(0);
        if (t == NT - 2) asm volatile("s_waitcnt vmcnt(0)" ::: "memory");
        else             asm volatile("s_waitcnt vmcnt(8)" ::: "memory");
        __builtin_amdgcn_s_barrier();
        asm volatile("" ::: "memory");
    }

#pragma unroll
    for (int mh = 0; mh < 2; mh++)
#pragma unroll
        for (int nh = 0; nh < 2; nh++)
#pragma unroll
            for (int fi = 0; fi < 4; fi++)
#pragma unroll
                for (int fj = 0; fj < 2; fj++)
#pragma unroll
                    for (int r = 0; r < 4; r++) {
                        int row = im * 256 + mh * 128 + wm * 64 + fi * 16 + lq * 4 + r;
                        int col = in * 256 + nh * 128 + wn * 32 + fj * 16 + lr;
                        epi_store<EPI>(acc[mh][nh][fi][fj][r], row, col, Cv, ldc, bias);
                    }
}

// ---------- BMxBN weight GEMM (QKV / proj / FC / FC2) ----------
template <int BM, int BN, int BK, int EPI, bool SWZG>
__global__ __launch_bounds__(256) void gemm_fast(
    const bf16* __restrict__ A, int lda,
    const bf16* __restrict__ Bm, int ldb,
    void* __restrict__ Cv, int ldc,
    const float* __restrict__ bias, int K)
{
    static_assert(BK == 64, "staging geometry assumes BK=64");
    __shared__ alignas(16) bf16 As[2][BM][BK];
    __shared__ alignas(16) bf16 Bs[2][BN][BK];

    const int tid = threadIdx.x;
    const int lane = tid & 63;
    const int w = tid >> 6;
    const int wm = w >> 1, wn = w & 1;
    constexpr int WM = BM / 2, WN = BN / 2;
    constexpr int FM = WM / 16, FN = WN / 16;
    constexpr int RPI = 512 / BK;
    constexpr int AI = BM / (4 * RPI);
    constexpr int BI = BN / (4 * RPI);

    int im, in;
    if constexpr (SWZG) {
        int nwg = gridDim.x * gridDim.y;
        int orig = blockIdx.y * gridDim.x + blockIdx.x;
        int q = nwg >> 3, rr = nwg & 7, xcd = orig & 7, lid = orig >> 3;
        int wg = (xcd < rr ? xcd * (q + 1) : rr * (q + 1) + (xcd - rr) * q) + lid;
        im = wg % gridDim.x;
        in = wg / gridDim.x;
    } else {
        im = blockIdx.y;
        in = blockIdx.x;
    }

    const bf16* Ab = A + (size_t)im * BM * lda;
    const bf16* Bb = Bm + (size_t)in * BN * ldb;

    const int sr = lane >> 3;
    const int scs = (((lane & 7) ^ sr) * 8);
    const int lr = lane & 15, lq = lane >> 4;

    f32x4 acc[FM][FN];
#pragma unroll
    for (int i = 0; i < FM; i++)
#pragma unroll
        for (int j = 0; j < FN; j++) acc[i][j] = (f32x4){0.f, 0.f, 0.f, 0.f};

    auto stage = [&](int buf, int k0) {
#pragma unroll
        for (int i = 0; i < AI; i++) {
            int row = (w * AI + i) * RPI;
            gl2lds16(Ab + (size_t)(row + sr) * lda + k0 + scs, &As[buf][row][0]);
        }
#pragma unroll
        for (int i = 0; i < BI; i++) {
            int row = (w * BI + i) * RPI;
            gl2lds16(Bb + (size_t)(row + sr) * ldb + k0 + scs, &Bs[buf][row][0]);
        }
    };

    const int NT = K / BK;
    stage(0, 0);
    __syncthreads();

    for (int t = 0; t < NT; t++) {
        const int cur = t & 1;
        if (t + 1 < NT) stage(cur ^ 1, (t + 1) * BK);

        const char* Abase = (const char*)&As[cur][0][0];
        const char* Bbase = (const char*)&Bs[cur][0][0];
#pragma unroll
        for (int kk = 0; kk < BK / 32; kk++) {
            short8 af[FM], bfr[FN];
#pragma unroll
            for (int i = 0; i < FM; i++) {
                int r = wm * WM + i * 16 + lr;
                int cb = (kk * 64 + lq * 16) ^ ((r & 7) << 4);
                af[i] = *reinterpret_cast<const short8*>(Abase + (size_t)r * (BK * 2) + cb);
            }
#pragma unroll
            for (int j = 0; j < FN; j++) {
                int r = wn * WN + j * 16 + lr;
                int cb = (kk * 64 + lq * 16) ^ ((r & 7) << 4);
                bfr[j] = *reinterpret_cast<const short8*>(Bbase + (size_t)r * (BK * 2) + cb);
            }
#pragma unroll
            for (int i = 0; i < FM; i++)
#pragma unroll
                for (int j = 0; j < FN; j++)
                    acc[i][j] = __builtin_amdgcn_mfma_f32_16x16x32_bf16(af[i], bfr[j], acc[i][j], 0, 0, 0);
        }
        __syncthreads();
    }

#pragma unroll
    for (int i = 0; i < FM; i++)
#pragma unroll
        for (int j = 0; j < FN; j++)
#pragma unroll
            for (int r = 0; r < 4; r++) {
                int row = im * BM + wm * WM + i * 16 + lq * 4 + r;
                int col = in * BN + wn * WN + j * 16 + lr;
                epi_store<EPI>(acc[i][j][r], row, col, Cv, ldc, bias);
            }
}

// ---------- slow lm_head fallback (B fp32) ----------
template <int BM, int BN, int BK, int EPI>
__global__ __launch_bounds__(256) void gemm_bt_f32(
    const bf16* __restrict__ A, int lda,
    const float* __restrict__ Bm, int ldb,
    void* __restrict__ Cv, int ldc,
    const float* __restrict__ bias, int K)
{
    constexpr int BKP = BK + 8;
    __shared__ bf16 As[BM][BKP];
    __shared__ bf16 Bs[BN][BKP];
    const int tid = threadIdx.x;
    const int lane = tid & 63;
    const int w = tid >> 6;
    const int wm = w >> 1, wn = w & 1;
    constexpr int WM = BM / 2, WN = BN / 2;
    constexpr int FM = WM / 16, FN = WN / 16;
    const int bx = blockIdx.x, by = blockIdx.y;
    const bf16* Ab = A + (size_t)by * BM * lda;
    const float* Bb = Bm + (size_t)bx * BN * ldb;
    f32x4 acc[FM][FN];
#pragma unroll
    for (int i = 0; i < FM; i++)
#pragma unroll
        for (int j = 0; j < FN; j++) acc[i][j] = (f32x4){0.f, 0.f, 0.f, 0.f};
    const int lr = lane & 15, lq = lane >> 4;
    for (int k0 = 0; k0 < K; k0 += BK) {
        constexpr int AC = (BM * BK) / (256 * 8);
#pragma unroll
        for (int i = 0; i < AC; i++) {
            int c = tid + i * 256;
            int row = c / (BK / 8);
            int kc = (c % (BK / 8)) * 8;
            *reinterpret_cast<int4*>(&As[row][kc]) =
                *reinterpret_cast<const int4*>(Ab + (size_t)row * lda + k0 + kc);
        }
        constexpr int BC = (BN * BK) / (256 * 4);
#pragma unroll
        for (int i = 0; i < BC; i++) {
            int c = tid + i * 256;
            int row = c / (BK / 4);
            int kc = (c % (BK / 4)) * 4;
            float4 v = *reinterpret_cast<const float4*>(Bb + (size_t)row * ldb + k0 + kc);
            unsigned long long p = (unsigned long long)f2bu(v.x) |
                                   ((unsigned long long)f2bu(v.y) << 16) |
                                   ((unsigned long long)f2bu(v.z) << 32) |
                                   ((unsigned long long)f2bu(v.w) << 48);
            *reinterpret_cast<unsigned long long*>(&Bs[row][kc]) = p;
        }
        __syncthreads();
#pragma unroll
        for (int kk = 0; kk < BK / 32; kk++) {
            short8 af[FM], bfr[FN];
#pragma unroll
            for (int i = 0; i < FM; i++)
                af[i] = *reinterpret_cast<const short8*>(&As[wm * WM + i * 16 + lr][kk * 32 + lq * 8]);
#pragma unroll
            for (int j = 0; j < FN; j++)
                bfr[j] = *reinterpret_cast<const short8*>(&Bs[wn * WN + j * 16 + lr][kk * 32 + lq * 8]);
#pragma unroll
            for (int i = 0; i < FM; i++)
#pragma unroll
                for (int j = 0; j < FN; j++)
                    acc[i][j] = __builtin_amdgcn_mfma_f32_16x16x32_bf16(af[i], bfr[j], acc[i][j], 0, 0, 0);
        }
        __syncthreads();
    }
#pragma unroll
    for (int i = 0; i < FM; i++)
#pragma unroll
        for (int j = 0; j < FN; j++)
#pragma unroll
            for (int r = 0; r < 4; r++) {
                int row = by * BM + wm * WM + i * 16 + lq * 4 + r;
                int col = bx * BN + wn * WN + j * 16 + lr;
                epi_store<EPI>(acc[i][j][r], row, col, Cv, ldc, bias);
            }
}

// ---------- flash attention: single-buffered + XCD-chunked z-grouping ----------
__global__ __launch_bounds__(256) void flash_attn(
    const bf16* __restrict__ q, const bf16* __restrict__ kbuf,
    const bf16* __restrict__ vt, bf16* __restrict__ y)
{
    __shared__ alignas(16) bf16 Ks[128 * 64];
    __shared__ alignas(16) bf16 Vs[64 * 128];
    __shared__ alignas(16) bf16 Ps[4 * 16 * 136];

    const int tid = threadIdx.x;
    const int lane = tid & 63;
    const int w = tid >> 6;
    const int lr = lane & 15, lq = lane >> 4;

    int flat = blockIdx.y * gridDim.x + blockIdx.x;
    int xcd = flat & 7, lid = flat >> 3;
    int wg = xcd * 64 + lid;
    const int z = wg >> 4;
    const int qi = 15 - (wg & 15);
    const int b = z >> 4, h = z & 15;
    const float slope = exp2f(-0.5f * (float)(h + 1));

    const bf16* qz = q + (size_t)z * (Tc * HDc);
    const bf16* kz = kbuf + (size_t)z * (Tc * HDc);
    const bf16* vz = vt + (size_t)z * (HDc * Tc);

    const int rowbase = qi * 64 + w * 16;

    short8 qf[2];
#pragma unroll
    for (int kk = 0; kk < 2; kk++)
        qf[kk] = *reinterpret_cast<const short8*>(
            qz + (size_t)(rowbase + lr) * HDc + kk * 32 + lq * 8);

    float m_old[4], l_sum[4];
#pragma unroll
    for (int r = 0; r < 4; r++) { m_old[r] = -3.0e38f; l_sum[r] = 0.f; }
    f32x4 o[4];
#pragma unroll
    for (int dj = 0; dj < 4; dj++) o[dj] = (f32x4){0.f, 0.f, 0.f, 0.f};

    bf16* Pw = Ps + w * 16 * 136;

    const int nkv = (qi * 64 + 63) / 128 + 1;
    for (int kv = 0; kv < nkv; kv++) {
#pragma unroll
        for (int i = 0; i < 4; i++) {
            int rbase = w * 32 + i * 8;
            int row = rbase + (lane >> 3);
            int slot = lane & 7;
            gl2lds16(kz + (size_t)(kv * 128 + row) * HDc + ((slot ^ (row & 7)) * 8),
                     &Ks[rbase * 64]);
        }
#pragma unroll
        for (int i = 0; i < 4; i++) {
            int rbase = w * 16 + i * 4;
            int row = rbase + lq;
            gl2lds16(vz + (size_t)row * Tc + kv * 128 + ((lr ^ (row & 7)) * 8),
                     &Vs[rbase * 128]);
        }
        __syncthreads();

        f32x4 s[8];
#pragma unroll
        for (int j = 0; j < 8; j++) s[j] = (f32x4){0.f, 0.f, 0.f, 0.f};
#pragma unroll
        for (int kk = 0; kk < 2; kk++) {
#pragma unroll
            for (int j = 0; j < 8; j++) {
                int row = j * 16 + lr;
                int cb = ((kk * 4 + lq) ^ (row & 7)) << 4;
                short8 bfr = *reinterpret_cast<const short8*>(
                    (const char*)Ks + row * 128 + cb);
                s[j] = __builtin_amdgcn_mfma_f32_16x16x32_bf16(qf[kk], bfr, s[j], 0, 0, 0);
            }
        }

        float mt[4];
#pragma unroll
        for (int r = 0; r < 4; r++) mt[r] = -3.0e38f;
#pragma unroll
        for (int j = 0; j < 8; j++) {
            int col = kv * 128 + j * 16 + lr;
#pragma unroll
            for (int r = 0; r < 4; r++) {
                int rowg = rowbase + lq * 4 + r;
                float v = s[j][r] * 0.125f - (float)(rowg - col) * slope;
                v = (col > rowg) ? -3.0e38f : v;
                s[j][r] = v;
                mt[r] = fmaxf(mt[r], v);
            }
        }
#pragma unroll
        for (int r = 0; r < 4; r++)
#pragma unroll
            for (int off = 1; off < 16; off <<= 1)
                mt[r] = fmaxf(mt[r], __shfl_xor(mt[r], off));

        float f[4], rs[4];
#pragma unroll
        for (int r = 0; r < 4; r++) {
            float mn = fmaxf(m_old[r], mt[r]);
            f[r] = __expf(m_old[r] - mn);
            m_old[r] = mn;
            rs[r] = 0.f;
        }
#pragma unroll
        for (int j = 0; j < 8; j++)
#pragma unroll
            for (int r = 0; r < 4; r++) {
                float p = __expf(s[j][r] - m_old[r]);
                s[j][r] = p;
                rs[r] += p;
            }
#pragma unroll
        for (int r = 0; r < 4; r++) {
#pragma unroll
            for (int off = 1; off < 16; off <<= 1)
                rs[r] += __shfl_xor(rs[r], off);
            l_sum[r] = l_sum[r] * f[r] + rs[r];
        }

#pragma unroll
        for (int j = 0; j < 8; j++)
#pragma unroll
            for (int r = 0; r < 4; r++)
                Pw[(lq * 4 + r) * 136 + j * 16 + lr] = __float2bfloat16(s[j][r]);

#pragma unroll
        for (int dj = 0; dj < 4; dj++)
#pragma unroll
            for (int r = 0; r < 4; r++) o[dj][r] *= f[r];

        __syncthreads();

#pragma unroll
        for (int kk = 0; kk < 4; kk++) {
            short8 pa = *reinterpret_cast<const short8*>(
                (const char*)Pw + lr * 272 + kk * 64 + lq * 16);
#pragma unroll
            for (int dj = 0; dj < 4; dj++) {
                int row = dj * 16 + lr;
                int cb = ((kk * 4 + lq) ^ (row & 7)) << 4;
                short8 vb = *reinterpret_cast<const short8*>(
                    (const char*)Vs + row * 256 + cb);
                o[dj] = __builtin_amdgcn_mfma_f32_16x16x32_bf16(pa, vb, o[dj], 0, 0, 0);
            }
        }
        __syncthreads();
    }

#pragma unroll
    for (int dj = 0; dj < 4; dj++)
#pragma unroll
        for (int r = 0; r < 4; r++) {
            int rowg = rowbase + lq * 4 + r;
            float outv = o[dj][r] / l_sum[r];
            y[((size_t)b * Tc + rowg) * Dc + h * HDc + dj * 16 + lr] =
                __float2bfloat16(outv);
        }
}

// ---------- fused weight conversion ----------
constexpr long C_AW = 1572864;
constexpr long C_PW = C_AW + 524288;
constexpr long C_FW = C_PW + 2097152;
constexpr long C_F2 = C_FW + 2097152;
constexpr long C_LM = C_F2 + 4096000;

__device__ __forceinline__ void cvt8(const float* src, bf16* dst) {
    float4 a = *reinterpret_cast<const float4*>(src);
    float4 b = *reinterpret_cast<const float4*>(src + 4);
    unsigned long long p0 = (unsigned long long)f2bu(a.x) |
                            ((unsigned long long)f2bu(a.y) << 16) |
                            ((unsigned long long)f2bu(a.z) << 32) |
                            ((unsigned long long)f2bu(a.w) << 48);
    unsigned long long p1 = (unsigned long long)f2bu(b.x) |
                            ((unsigned long long)f2bu(b.y) << 16) |
                            ((unsigned long long)f2bu(b.z) << 32) |
                            ((unsigned long long)f2bu(b.w) << 48);
    *reinterpret_cast<unsigned long long*>(dst) = p0;
    *reinterpret_cast<unsigned long long*>(dst + 4) = p1;
}

__global__ __launch_bounds__(256) void f2b8_multi(
    const float* aw, bf16* awb, const float* pw, bf16* pwb,
    const float* fw, bf16* fwb, const float* f2, bf16* f2b,
    const float* lm, bf16* lmb, long total) {
    long i = (long)blockIdx.x * 256 + threadIdx.x;
    if (i >= total) return;
    if (i < C_AW)      cvt8(aw + i * 8, awb + i * 8);
    else if (i < C_PW) { long j = i - C_AW; cvt8(pw + j * 8, pwb + j * 8); }
    else if (i < C_FW) { long j = i - C_PW; cvt8(fw + j * 8, fwb + j * 8); }
    else if (i < C_F2) { long j = i - C_FW; cvt8(f2 + j * 8, f2b + j * 8); }
    else               { long j = i - C_F2; cvt8(lm + j * 8, lmb + j * 8); }
}

__global__ __launch_bounds__(256) void embed_kernel(const int* __restrict__ ids,
                                                    const float* __restrict__ wte,
                                                    bf16* __restrict__ x) {
    int row = blockIdx.x;
    int t = threadIdx.x;
    int id = ids[row];
    float4 v = reinterpret_cast<const float4*>(wte + (size_t)id * Dc)[t];
    unsigned long long p = (unsigned long long)f2bu(v.x) |
                           ((unsigned long long)f2bu(v.y) << 16) |
                           ((unsigned long long)f2bu(v.z) << 32) |
                           ((unsigned long long)f2bu(v.w) << 48);
    *reinterpret_cast<unsigned long long*>(x + (size_t)row * Dc + t * 4) = p;
}

__global__ __launch_bounds__(256) void ln_kernel(const bf16* __restrict__ x,
                                                 const float* __restrict__ g,
                                                 const float* __restrict__ b,
                                                 bf16* __restrict__ out) {
    int row = blockIdx.x;
    int t = threadIdx.x;
    unsigned long long uv = *reinterpret_cast<const unsigned long long*>(
        x + (size_t)row * Dc + t * 4);
    float vv[4];
#pragma unroll
    for (int j = 0; j < 4; j++) vv[j] = bu2f((unsigned short)(uv >> (16 * j)));
    float s = vv[0] + vv[1] + vv[2] + vv[3];
    float s2 = vv[0] * vv[0] + vv[1] * vv[1] + vv[2] * vv[2] + vv[3] * vv[3];
#pragma unroll
    for (int o = 32; o > 0; o >>= 1) {
        s += __shfl_down(s, o);
        s2 += __shfl_down(s2, o);
    }
    __shared__ float sm[8];
    int wid = t >> 6, ln = t & 63;
    if (ln == 0) { sm[wid] = s; sm[4 + wid] = s2; }
    __syncthreads();
    if (t == 0) {
        float ts = sm[0] + sm[1] + sm[2] + sm[3];
        float ts2 = sm[4] + sm[5] + sm[6] + sm[7];
        sm[0] = ts; sm[4] = ts2;
    }
    __syncthreads();
    float mean = sm[0] * (1.0f / Dc);
    float var = sm[4] * (1.0f / Dc) - mean * mean;
    float rstd = rsqrtf(var + 1e-5f);
    int c0 = t * 4;
    unsigned long long p = 0;
#pragma unroll
    for (int j = 0; j < 4; j++) {
        float val = (vv[j] - mean) * rstd * g[c0 + j] + b[c0 + j];
        p |= (unsigned long long)f2bu(val) << (16 * j);
    }
    *reinterpret_cast<unsigned long long*>(out + (size_t)row * Dc + c0) = p;
}

__global__ __launch_bounds__(256) void v2vt(const bf16* __restrict__ v,
                                            bf16* __restrict__ vt) {
    int idx = blockIdx.x * 256 + threadIdx.x;
    int tc = idx & 127;
    int t0 = tc * 8;
    int rest = idx >> 7;
    int hd = rest & 63;
    int z = rest >> 6;
    const bf16* src = v + ((size_t)z * Tc) * HDc + hd;
    unsigned long long p0 = 0, p1 = 0;
#pragma unroll
    for (int i = 0; i < 4; i++) {
        unsigned short u;
        __builtin_memcpy(&u, src + (size_t)(t0 + i) * HDc, 2);
        p0 |= (unsigned long long)u << (16 * i);
    }
#pragma unroll
    for (int i = 0; i < 4; i++) {
        unsigned short u;
        __builtin_memcpy(&u, src + (size_t)(t0 + 4 + i) * HDc, 2);
        p1 |= (unsigned long long)u << (16 * i);
    }
    bf16* dst = vt + ((size_t)z * HDc + hd) * Tc + t0;
    *reinterpret_cast<unsigned long long*>(dst) = p0;
    *reinterpret_cast<unsigned long long*>(dst + 4) = p1;
}

extern "C" void kernel_launch(void* const* d_in, const int* in_sizes, int n_in,
                              void* d_out, int out_size, void* d_ws, size_t ws_size,
                              hipStream_t stream) {
    const int* ids = (const int*)d_in[0];
    const float* wte = (const float*)d_in[1];
    const float* ln1g = (const float*)d_in[2];
    const float* ln1b = (const float*)d_in[3];
    const float* attw = (const float*)d_in[4];
    const float* attb = (const float*)d_in[5];
    const float* projw = (const float*)d_in[6];
    const float* projb = (const float*)d_in[7];
    const float* ln2g = (const float*)d_in[8];
    const float* ln2b = (const float*)d_in[9];
    const float* fcw = (const float*)d_in[10];
    const float* fcb = (const float*)d_in[11];
    const float* fc2w = (const float*)d_in[12];
    const float* fc2b = (const float*)d_in[13];
    const float* lnfg = (const float*)d_in[14];
    const float* lnfb = (const float*)d_in[15];
    const float* lmw = (const float*)d_in[16];

    const int M = Bc * Tc;  // 2048
    char* ws = (char*)d_ws;
    size_t off = 0;
    auto carve = [&](size_t bytes) { char* p = ws + off; off += (bytes + 255) & ~(size_t)255; return p; };

    bf16* x = (bf16*)carve((size_t)M * Dc * 2);
    bf16* h = (bf16*)carve((size_t)M * Dc * 2);
    bf16* qkvb = (bf16*)carve((size_t)3 * 2097152 * 2);
    bf16* vt = (bf16*)carve((size_t)Bc * Hc * HDc * Tc * 2);
    bf16* y = (bf16*)carve((size_t)M * Dc * 2);
    bf16* mlp = (bf16*)carve((size_t)M * MLPc * 2);
    bf16* q = qkvb;
    bf16* kb = qkvb + 2097152;
    bf16* vtmp = qkvb + 4194304;

    const long nLM = (long)Vc * Dc;
    bool has_wlm = ws_size >= off + (size_t)nLM * 2;
    bf16* wlm = nullptr;
    if (has_wlm) wlm = (bf16*)carve((size_t)nLM * 2);

    const long nAW = (long)Lc * 3 * Dc * Dc;
    const long nPW = (long)Lc * Dc * Dc;
    const long nFW = (long)Lc * MLPc * Dc;
    const long nF2W = (long)Lc * Dc * MLPc;
    bf16* awAll = (bf16*)d_out;
    bf16* pwAll = awAll + nAW;
    bf16* fwAll = pwAll + nPW;
    bf16* f2wAll = fwAll + nFW;

    embed_kernel<<<M, 256, 0, stream>>>(ids, wte, x);

    const long totChunks = has_wlm ? C_LM : C_F2;
    f2b8_multi<<<(int)((totChunks + 255) / 256), 256, 0, stream>>>(
        attw, awAll, projw, pwAll, fcw, fwAll, fc2w, f2wAll,
        lmw, wlm, totChunks);

    for (int l = 0; l < Lc; l++) {
        bf16* aw_b = awAll + (size_t)l * 3 * Dc * Dc;
        bf16* pw_b = pwAll + (size_t)l * Dc * Dc;
        bf16* fw_b = fwAll + (size_t)l * MLPc * Dc;
        bf16* f2w_b = f2wAll + (size_t)l * Dc * MLPc;

        ln_kernel<<<M, 256, 0, stream>>>(x, ln1g + l * Dc, ln1b + l * Dc, h);

        gemm_fast<128, 64, 64, EPI_QKV, true>
            <<<dim3(M / 128, 3 * Dc / 64, 1), 256, 0, stream>>>(
                h, Dc, aw_b, Dc, qkvb, 0, attb + l * 3 * Dc, Dc);

        v2vt<<<(Bc * Hc * HDc * (Tc / 8)) / 256, 256, 0, stream>>>(vtmp, vt);

        flash_attn<<<dim3(Tc / 64, Bc * Hc), 256, 0, stream>>>(q, kb, vt, y);

        // proj: 64x64 tile -> 32x16 = 512 blocks = 2/CU
        gemm_fast<64, 64, 64, EPI_RESADD, true>
            <<<dim3(M / 64, Dc / 64, 1), 256, 0, stream>>>(
                y, Dc, pw_b, Dc, x, Dc, projb + l * Dc, Dc);

        ln_kernel<<<M, 256, 0, stream>>>(x, ln2g + l * Dc, ln2b + l * Dc, h);

        // fc: BN=64 -> 16x64 = 1024 blocks = 4/CU
        gemm_fast<128, 64, 64, EPI_GELU, true>
            <<<dim3(M / 128, MLPc / 64, 1), 256, 0, stream>>>(
                h, Dc, fw_b, Dc, mlp, MLPc, fcb + l * MLPc, Dc);

        // fc2: 64x64 tile -> 32x16 = 512 blocks = 2/CU
        gemm_fast<64, 64, 64, EPI_RESADD, true>
            <<<dim3(M / 64, Dc / 64, 1), 256, 0, stream>>>(
                mlp, MLPc, f2w_b, MLPc, x, Dc, fc2b + l * Dc, MLPc);
    }

    ln_kernel<<<M, 256, 0, stream>>>(x, lnfg, lnfb, h);

    if (has_wlm)
        gemm_8p<EPI_F32>
            <<<dim3(M / 256, Vc / 256, 1), 512, 0, stream>>>(
                h, Dc, wlm, Dc, (float*)d_out, Vc, nullptr, Dc);
    else
        gemm_bt_f32<128, 128, 64, EPI_F32>
            <<<dim3(Vc / 128, M / 128, 1), 256, 0, stream>>>(
                h, Dc, lmw, Dc, (float*)d_out, Vc, nullptr, Dc);
}